// Round 6
// baseline (160.513 us; speedup 1.0000x reference)
//
#include <hip/hip_runtime.h>

#define N_NODES 50000
#define N_EDGES 625000
#define DIM 128
#define RCAP 16           // ushort slots per (node, xcd) sub-bucket (32 B)
#define OCAP 64           // global overflow slots per node (~never used)

typedef __bf16 bf16x8 __attribute__((ext_vector_type(8)));
typedef __bf16 bf16x4 __attribute__((ext_vector_type(4)));
typedef __bf16 bf16x2 __attribute__((ext_vector_type(2)));
typedef float f32x4 __attribute__((ext_vector_type(4)));

__device__ __forceinline__ float bflo(unsigned u) { return __uint_as_float(u << 16); }
__device__ __forceinline__ float bfhi(unsigned u) { return __uint_as_float(u & 0xffff0000u); }

// ===========================================================================
// K-FILL: bucket-CSR fill, ALONE on the machine (R6 split).
// R3/R5 established: fill is random-HBM-bound (1.5 TB/s @ 66 MB), with 37 MB
// write amplification = one 64B line evicted per scattered 4B store (same-line
// stores arrive too far apart; co-resident GEMM1 thrashed L2 in between).
// Fix: per-XCD working set (1.6 MB ushort bucket slice + 0.2 MB counters)
// fits the 4 MB L2 with no competing traffic -> stores coalesce in L2, each
// line written back once.
// Block 0 also zeroes h row N_NODES and converts W_phy -> bf16 Wb.
// ===========================================================================
__global__ __launch_bounds__(512) void fill_k(
    const int* __restrict__ src,
    const int* __restrict__ dst,
    int* __restrict__ cnt9,            // [8][N] region counters + [8N..) overflow counters
    unsigned short* __restrict__ bucket,  // [8][N][RCAP] ushort
    int* __restrict__ obucket,         // [N][OCAP]
    const float* __restrict__ W_phy,
    __bf16* __restrict__ Wb,
    __bf16* __restrict__ out_bf16)
{
    const int t = threadIdx.x;

    if (blockIdx.x == 0) {
        if (t < 16) {
            bf16x8 z = {};
            *(bf16x8*)&out_bf16[(size_t)N_NODES * DIM + t * 8] = z;
        }
        for (int i = t; i < 4096; i += 512) {
            float4 f = ((const float4*)W_phy)[i];
            bf16x4 pk = { (__bf16)f.x, (__bf16)f.y, (__bf16)f.z, (__bf16)f.w };
            *(bf16x4*)&Wb[i * 4] = pk;
        }
    }

    int xcd;
    asm volatile("s_getreg_b32 %0, hwreg(HW_REG_XCC_ID)" : "=s"(xcd));
    xcd &= 7;
    const int cb = xcd * N_NODES;

    const int idx = (int)blockIdx.x * 512 + t;
    if (idx < N_EDGES / 8) {                        // 625000 = 8 * 78125
        int4 sa = ((const int4*)src)[idx * 2];
        int4 sb = ((const int4*)src)[idx * 2 + 1];
        int4 da = ((const int4*)dst)[idx * 2];
        int4 db = ((const int4*)dst)[idx * 2 + 1];
        // returning atomics back-to-back (XCD-local counter lines, L2-resident)
        int p0 = atomicAdd(&cnt9[cb + da.x], 1);
        int p1 = atomicAdd(&cnt9[cb + da.y], 1);
        int p2 = atomicAdd(&cnt9[cb + da.z], 1);
        int p3 = atomicAdd(&cnt9[cb + da.w], 1);
        int p4 = atomicAdd(&cnt9[cb + db.x], 1);
        int p5 = atomicAdd(&cnt9[cb + db.y], 1);
        int p6 = atomicAdd(&cnt9[cb + db.z], 1);
        int p7 = atomicAdd(&cnt9[cb + db.w], 1);
        // 2B stores into the XCD-local, L2-resident bucket slice
        if (p0 < RCAP) bucket[((cb + da.x) << 4) + p0] = (unsigned short)sa.x;
        else { int q = atomicAdd(&cnt9[8 * N_NODES + da.x], 1); obucket[(da.x << 6) + q] = sa.x; }
        if (p1 < RCAP) bucket[((cb + da.y) << 4) + p1] = (unsigned short)sa.y;
        else { int q = atomicAdd(&cnt9[8 * N_NODES + da.y], 1); obucket[(da.y << 6) + q] = sa.y; }
        if (p2 < RCAP) bucket[((cb + da.z) << 4) + p2] = (unsigned short)sa.z;
        else { int q = atomicAdd(&cnt9[8 * N_NODES + da.z], 1); obucket[(da.z << 6) + q] = sa.z; }
        if (p3 < RCAP) bucket[((cb + da.w) << 4) + p3] = (unsigned short)sa.w;
        else { int q = atomicAdd(&cnt9[8 * N_NODES + da.w], 1); obucket[(da.w << 6) + q] = sa.w; }
        if (p4 < RCAP) bucket[((cb + db.x) << 4) + p4] = (unsigned short)sb.x;
        else { int q = atomicAdd(&cnt9[8 * N_NODES + db.x], 1); obucket[(db.x << 6) + q] = sb.x; }
        if (p5 < RCAP) bucket[((cb + db.y) << 4) + p5] = (unsigned short)sb.y;
        else { int q = atomicAdd(&cnt9[8 * N_NODES + db.y], 1); obucket[(db.y << 6) + q] = sb.y; }
        if (p6 < RCAP) bucket[((cb + db.z) << 4) + p6] = (unsigned short)sb.z;
        else { int q = atomicAdd(&cnt9[8 * N_NODES + db.z], 1); obucket[(db.z << 6) + q] = sb.z; }
        if (p7 < RCAP) bucket[((cb + db.w) << 4) + p7] = (unsigned short)sb.w;
        else { int q = atomicAdd(&cnt9[8 * N_NODES + db.w], 1); obucket[(db.w << 6) + q] = sb.w; }
    }
}

// ===========================================================================
// K-GEMM1: bf16 MFMA GEMM1 + bias + relu -> h (bf16), ALONE (clean L2 for
// streaming A). Structure proven since R10 of the previous session.
// ===========================================================================
__global__ __launch_bounds__(512) void gemm1_k(
    const float* __restrict__ A_f32,
    const float* __restrict__ W,
    const float* __restrict__ bias,
    __bf16* __restrict__ out_bf16)
{
    const int t = threadIdx.x;
    __shared__ __align__(16) __bf16 w_lds[128 * 136];   // 34.8 KB

    for (int i = t; i < 4096; i += 512) {               // 8 iters
        float4 f = ((const float4*)W)[i];
        int n = i >> 5;
        int k = (i & 31) << 2;
        bf16x4 pk = { (__bf16)f.x, (__bf16)f.y, (__bf16)f.z, (__bf16)f.w };
        *(bf16x4*)&w_lds[n * 136 + k] = pk;             // ds_write_b64
    }
    __syncthreads();

    const int wave = t >> 6;           // 0..7
    const int lane = t & 63;
    const int q = lane >> 4;
    const int mr = lane & 15;

    const int m0 = blockIdx.x * 128 + wave * 16;
    int arow = m0 + mr;
    if (arow >= N_NODES) arow = N_NODES - 1;

    f32x4 acc[8] = {};

#pragma unroll
    for (int ks = 0; ks < 4; ++ks) {
        const int k0 = ks * 32 + q * 8;
        const float4* ap = (const float4*)&A_f32[(size_t)arow * DIM + k0];
        float4 a0 = ap[0], a1 = ap[1];
        bf16x8 af;
        af[0] = (__bf16)a0.x; af[1] = (__bf16)a0.y;
        af[2] = (__bf16)a0.z; af[3] = (__bf16)a0.w;
        af[4] = (__bf16)a1.x; af[5] = (__bf16)a1.y;
        af[6] = (__bf16)a1.z; af[7] = (__bf16)a1.w;
#pragma unroll
        for (int nt = 0; nt < 8; ++nt) {
            bf16x8 bfr = *(const bf16x8*)&w_lds[(nt * 16 + mr) * 136 + k0];
            acc[nt] = __builtin_amdgcn_mfma_f32_16x16x32_bf16(af, bfr, acc[nt], 0, 0, 0);
        }
    }

    __syncthreads();                   // all w_lds reads done
    float* lds_f = (float*)w_lds;      // 64 x 132 fp32 buffer
    const int nb = blockIdx.x * 128;

#pragma unroll
    for (int half = 0; half < 2; ++half) {
        if ((wave >> 2) == half) {
            int lw = wave & 3;
#pragma unroll
            for (int nt = 0; nt < 8; ++nt)
#pragma unroll
                for (int r = 0; r < 4; ++r)
                    lds_f[(lw * 16 + q * 4 + r) * 132 + nt * 16 + mr] = acc[nt][r];
        }
        __syncthreads();
        for (int i = t; i < 2048; i += 512) {
            int lr = i >> 5;
            int cg = (i & 31) << 2;
            int grow = nb + half * 64 + lr;
            if (grow < N_NODES) {
                float4 v = *(const float4*)&lds_f[lr * 132 + cg];
                float4 b4 = *(const float4*)&bias[cg];
                bf16x4 o;
                o[0] = (__bf16)fmaxf(v.x + b4.x, 0.f);
                o[1] = (__bf16)fmaxf(v.y + b4.y, 0.f);
                o[2] = (__bf16)fmaxf(v.z + b4.z, 0.f);
                o[3] = (__bf16)fmaxf(v.w + b4.w, 0.f);
                *(bf16x4*)&out_bf16[(size_t)grow * DIM + cg] = o;
            }
        }
        __syncthreads();
    }
}

// ===========================================================================
// K2+K3 FUSED (R3 structure; R6 delta: bucket payload is ushort, read while
// still L2-hot from the immediately-preceding fill dispatch).
// ===========================================================================
__global__ __launch_bounds__(512, 4) void agg_gemm2_k(
    const __bf16* __restrict__ h,
    const int* __restrict__ cnt9,
    const unsigned short* __restrict__ bucket,
    const int* __restrict__ obucket,
    const float* __restrict__ eps_p,
    const __bf16* __restrict__ Wb,
    const float* __restrict__ bias,
    float* __restrict__ out)
{
    __shared__ __align__(16) __bf16 lds[2 * 128 * 136];   // 69.6 KB: [W | A]
    __shared__ __align__(16) int widx_all[8][200];        // 6.4 KB gather lists
    __bf16* const w_lds = lds;
    __bf16* const a_lds = lds + 128 * 136;

    const int t = threadIdx.x;

    // ---- stage W tile (issued first; drains under the aggregation phase) ----
    for (int i = t; i < 2048; i += 512) {               // 4 iters, b128 copy
        int n = i >> 4;
        int kk = (i & 15) << 3;
        bf16x8 v = *(const bf16x8*)&Wb[n * DIM + kk];
        *(bf16x8*)&w_lds[n * 136 + kk] = v;
    }

    const int wave = t >> 6;
    const int lane = t & 63;
    const int ch = lane << 1;                           // 2 channels per lane
    const int xq = lane >> 4;                           // region quad 0..3
    const int sj = lane & 15;                           // slot within region
    const int rowbase = __builtin_amdgcn_readfirstlane(blockIdx.x * 128 + wave * 16);
    const float eps = eps_p[0];
    int* const widx = widx_all[wave];

    // 2-deep pipelined per-node loads
    int ndv[2], cAv[2], cBv[2], rAv[2], rBv[2], ocv[2];
    unsigned svv[2];
    auto nload = [&](int sl, int ii) {
        const int node = rowbase + ii;
        const int nd = (node < N_NODES) ? node : (N_NODES - 1);
        ndv[sl] = nd;
        int ca = cnt9[xq * N_NODES + nd];
        int cb = cnt9[(xq + 4) * N_NODES + nd];
        cAv[sl] = (ca < RCAP) ? ca : RCAP;
        cBv[sl] = (cb < RCAP) ? cb : RCAP;
        rAv[sl] = (int)bucket[((xq * N_NODES + nd) << 4) + sj];
        rBv[sl] = (int)bucket[(((xq + 4) * N_NODES + nd) << 4) + sj];
        ocv[sl] = cnt9[8 * N_NODES + nd];
        svv[sl] = *(const unsigned*)&h[(size_t)nd * DIM + ch];
    };
    nload(0, 0);

#pragma unroll
    for (int i = 0; i < 16; ++i) {
        if (i < 15) nload((i + 1) & 1, i + 1);
        const int sl = i & 1;
        const int nd = ndv[sl];

        // ---- compact the 8 sub-lists into widx[0..deg) ----
        const unsigned long long mA = __ballot(sj < cAv[sl]);
        const unsigned long long mB = __ballot(sj < cBv[sl]);
        const unsigned long long below = (1ull << lane) - 1ull;
        const int tA = __popcll(mA);
        int deg = tA + __popcll(mB);
        if (sj < cAv[sl]) widx[__popcll(mA & below)] = rAv[sl];
        if (sj < cBv[sl]) widx[tA + __popcll(mB & below)] = rBv[sl];
        const int oc = ocv[sl];
        if (oc > 0) {                                   // ~never taken
            if (lane < oc) widx[deg + lane] = obucket[(nd << 6) + lane];
            deg += oc;
        }
        if (lane < 8) widx[deg + lane] = N_NODES;       // zero-row pad for batch-8

        // ---- batch-8 gather (indices broadcast from LDS) ----
        float ax = 0.f, ay = 0.f;
        for (int e = 0; e < deg; e += 8) {
            int4 w0 = *(const int4*)&widx[e];
            int4 w1 = *(const int4*)&widx[e + 4];
            unsigned v0 = *(const unsigned*)&h[(size_t)w0.x * DIM + ch];
            unsigned v1 = *(const unsigned*)&h[(size_t)w0.y * DIM + ch];
            unsigned v2 = *(const unsigned*)&h[(size_t)w0.z * DIM + ch];
            unsigned v3 = *(const unsigned*)&h[(size_t)w0.w * DIM + ch];
            unsigned v4 = *(const unsigned*)&h[(size_t)w1.x * DIM + ch];
            unsigned v5 = *(const unsigned*)&h[(size_t)w1.y * DIM + ch];
            unsigned v6 = *(const unsigned*)&h[(size_t)w1.z * DIM + ch];
            unsigned v7 = *(const unsigned*)&h[(size_t)w1.w * DIM + ch];
            ax += (bflo(v0) + bflo(v1)) + (bflo(v2) + bflo(v3))
                + (bflo(v4) + bflo(v5)) + (bflo(v6) + bflo(v7));
            ay += (bfhi(v0) + bfhi(v1)) + (bfhi(v2) + bfhi(v3))
                + (bfhi(v4) + bfhi(v5)) + (bfhi(v6) + bfhi(v7));
        }
        ax = 1.0f + eps * bflo(svv[sl]) + ax;
        ay = 1.0f + eps * bfhi(svv[sl]) + ay;
        bf16x2 o; o[0] = (__bf16)ax; o[1] = (__bf16)ay;
        *(bf16x2*)&a_lds[(wave * 16 + i) * 136 + ch] = o;   // own-wave row
    }

    __syncthreads();            // W tile staged by all waves; A rows are own-wave

    const int q = lane >> 4;
    const int mr = lane & 15;

    f32x4 acc[8] = {};

#pragma unroll
    for (int ks = 0; ks < 4; ++ks) {
        const int k0 = ks * 32 + q * 8;
        bf16x8 af = *(const bf16x8*)&a_lds[(wave * 16 + mr) * 136 + k0];
#pragma unroll
        for (int nt = 0; nt < 8; ++nt) {
            bf16x8 bfr = *(const bf16x8*)&w_lds[(nt * 16 + mr) * 136 + k0];
            acc[nt] = __builtin_amdgcn_mfma_f32_16x16x32_bf16(af, bfr, acc[nt], 0, 0, 0);
        }
    }

    __syncthreads();                   // all w_lds/a_lds reads done
    float* lds_f = (float*)lds;        // reuse W half: 64 x 132 fp32
    const int nb = blockIdx.x * 128;

#pragma unroll
    for (int half = 0; half < 2; ++half) {
        if ((wave >> 2) == half) {
            int lw = wave & 3;
#pragma unroll
            for (int nt = 0; nt < 8; ++nt)
#pragma unroll
                for (int r = 0; r < 4; ++r)
                    lds_f[(lw * 16 + q * 4 + r) * 132 + nt * 16 + mr] = acc[nt][r];
        }
        __syncthreads();
        for (int i2 = t; i2 < 2048; i2 += 512) {
            int lr = i2 >> 5;
            int cg = (i2 & 31) << 2;
            int grow = nb + half * 64 + lr;
            if (grow < N_NODES) {
                float4 v = *(const float4*)&lds_f[lr * 132 + cg];
                float4 b4 = *(const float4*)&bias[cg];
                v.x = fmaxf(v.x + b4.x, 0.f);
                v.y = fmaxf(v.y + b4.y, 0.f);
                v.z = fmaxf(v.z + b4.z, 0.f);
                v.w = fmaxf(v.w + b4.w, 0.f);
                *(float4*)&out[(size_t)grow * DIM + cg] = v;
            }
        }
        __syncthreads();
    }
}

extern "C" void kernel_launch(void* const* d_in, const int* in_sizes, int n_in,
                              void* d_out, int out_size, void* d_ws, size_t ws_size,
                              hipStream_t stream) {
    const float* feats = (const float*)d_in[0];
    const int*   src   = (const int*)d_in[1];
    const int*   dst   = (const int*)d_in[2];
    const float* W_f   = (const float*)d_in[3];
    const float* b_f   = (const float*)d_in[4];
    const float* W_phy = (const float*)d_in[5];
    const float* b_phy = (const float*)d_in[6];
    const float* eps   = (const float*)d_in[7];
    float* out = (float*)d_out;

    const size_t HN = (size_t)(N_NODES + 1) * DIM;      // +1 zero row
    __bf16* h    = (__bf16*)d_ws;                                   // 12.8 MB
    unsigned short* bucket = (unsigned short*)(h + HN);             // 8*N*16*2B = 12.8 MB
    int* obucket = (int*)(bucket + (size_t)8 * N_NODES * RCAP);     // N*64 = 12.8 MB
    int* cnt9    = obucket + (size_t)N_NODES * OCAP;                // 9*N = 1.8 MB
    __bf16* Wb   = (__bf16*)(cnt9 + (size_t)9 * N_NODES);           // 32 KB

    const int gblocks = (N_NODES + 127) / 128;          // 391
    const int fblocks = (N_EDGES / 8 + 511) / 512;      // 153

    hipMemsetAsync(cnt9, 0, (size_t)9 * N_NODES * sizeof(int), stream);

    // Order: gemm1 (streaming, clean L2) -> fill (bucket stays L2-hot) -> agg
    gemm1_k<<<gblocks, 512, 0, stream>>>(feats, W_f, b_f, h);

    fill_k<<<fblocks, 512, 0, stream>>>(
        src, dst, cnt9, bucket, obucket, W_phy, Wb, h);

    agg_gemm2_k<<<gblocks, 512, 0, stream>>>(
        h, cnt9, bucket, obucket, eps, Wb, b_phy, out);
}

// Round 7
// 133.870 us; speedup vs baseline: 1.1990x; 1.1990x over previous
//
#include <hip/hip_runtime.h>

#define N_NODES 50000
#define N_EDGES 625000
#define DIM 128
#define NB 391            // coarse buckets = agg blocks (node >> 7)
#define BCAP 2048         // edges per bucket list (expected 1598, +11 sigma)

typedef __bf16 bf16x8 __attribute__((ext_vector_type(8)));
typedef __bf16 bf16x4 __attribute__((ext_vector_type(4)));
typedef __bf16 bf16x2 __attribute__((ext_vector_type(2)));
typedef float f32x4 __attribute__((ext_vector_type(4)));

__device__ __forceinline__ float bflo(unsigned u) { return __uint_as_float(u << 16); }
__device__ __forceinline__ float bfhi(unsigned u) { return __uint_as_float(u & 0xffff0000u); }

// ===========================================================================
// K1: fused [GEMM1 | two-level edge bucketing].
// R7 delta: per-edge global atomics ELIMINATED (R2/R3/R5/R6 killed every
// other fill theory; the invariant cost was 625k memory-side atomic RMWs).
// Fill now: LDS histogram over 391 coarse buckets (node>>7) -> LDS scan ->
// LDS scatter of packed (dstLow7<<16|src) edges -> copy-out with ONE global
// atomicAdd per (block,bucket) run (~60k total, 10x fewer) and contiguous
// burst writes. Bucket granularity == agg block node range, so agg gets a
// pre-localized edge list.
// ===========================================================================
__global__ __launch_bounds__(512) void gemm1_fill_k(
    const float* __restrict__ A_f32,
    const float* __restrict__ W,
    const float* __restrict__ bias,
    __bf16* __restrict__ out_bf16,
    const int* __restrict__ src,
    const int* __restrict__ dst,
    unsigned* __restrict__ blist,     // [NB][BCAP] packed edges
    int* __restrict__ bcnt,           // [NB] list lengths
    const float* __restrict__ W_phy,
    __bf16* __restrict__ Wb,
    int gemm_blocks)
{
    __shared__ __align__(16) __bf16 smem[128 * 136];    // 34.8 KB, both roles
    const int t = threadIdx.x;

    if ((int)blockIdx.x >= gemm_blocks) {
        // ---- fill role: LDS two-level bucketing ----
        int* hist       = (int*)smem;                   // [512]
        int* scanA      = hist + 512;                   // [512]
        int* rpB        = scanA + 512;                  // [512]
        int* offB       = rpB + 512;                    // [512]
        unsigned* stage = (unsigned*)(offB + 512);      // [4096]

        if ((int)blockIdx.x == gemm_blocks) {
            if (t < 16) {                               // zero row N_NODES of h
                bf16x8 z = {};
                *(bf16x8*)&out_bf16[(size_t)N_NODES * DIM + t * 8] = z;
            }
            for (int i = t; i < 4096; i += 512) {       // W_phy fp32 -> bf16
                float4 f = ((const float4*)W_phy)[i];
                bf16x4 pk = { (__bf16)f.x, (__bf16)f.y, (__bf16)f.z, (__bf16)f.w };
                *(bf16x4*)&Wb[i * 4] = pk;
            }
        }

        hist[t] = 0;
        __syncthreads();

        const int idx = ((int)blockIdx.x - gemm_blocks) * 512 + t;
        const bool valid = idx < N_EDGES / 8;           // 625000 = 8*78125
        unsigned pk[8];
        int bk[8];
        if (valid) {
            int4 sa = ((const int4*)src)[idx * 2];
            int4 sb = ((const int4*)src)[idx * 2 + 1];
            int4 da = ((const int4*)dst)[idx * 2];
            int4 db = ((const int4*)dst)[idx * 2 + 1];
            pk[0] = ((unsigned)(da.x & 127) << 16) | (unsigned)sa.x; bk[0] = da.x >> 7;
            pk[1] = ((unsigned)(da.y & 127) << 16) | (unsigned)sa.y; bk[1] = da.y >> 7;
            pk[2] = ((unsigned)(da.z & 127) << 16) | (unsigned)sa.z; bk[2] = da.z >> 7;
            pk[3] = ((unsigned)(da.w & 127) << 16) | (unsigned)sa.w; bk[3] = da.w >> 7;
            pk[4] = ((unsigned)(db.x & 127) << 16) | (unsigned)sb.x; bk[4] = db.x >> 7;
            pk[5] = ((unsigned)(db.y & 127) << 16) | (unsigned)sb.y; bk[5] = db.y >> 7;
            pk[6] = ((unsigned)(db.z & 127) << 16) | (unsigned)sb.z; bk[6] = db.z >> 7;
            pk[7] = ((unsigned)(db.w & 127) << 16) | (unsigned)sb.w; bk[7] = db.w >> 7;
#pragma unroll
            for (int j = 0; j < 8; ++j) atomicAdd(&hist[bk[j]], 1);   // LDS
        }
        __syncthreads();

        // Hillis-Steele inclusive scan over 512 slots (buckets 391..511 zero)
        const int hv = hist[t];
        scanA[t] = hv;
        __syncthreads();
        for (int d = 1; d < 512; d <<= 1) {
            int nv = scanA[t] + ((t >= d) ? scanA[t - d] : 0);
            __syncthreads();
            scanA[t] = nv;
            __syncthreads();
        }
        rpB[t] = scanA[t] - hv;                         // exclusive base
        offB[t] = scanA[t] - hv;                        // running cursor
        __syncthreads();

        if (valid) {
#pragma unroll
            for (int j = 0; j < 8; ++j) {
                int p = atomicAdd(&offB[bk[j]], 1);     // LDS
                stage[p] = pk[j];
            }
        }
        __syncthreads();

        // copy-out: one global atomic per (block,bucket) run, burst writes
        if (t < NB) {
            int n = hist[t];
            if (n > 0) {
                int gb = atomicAdd(&bcnt[t], n);        // ~60k total device-wide
                int lim = BCAP - gb;
                if (n > lim) n = (lim > 0) ? lim : 0;   // paranoia; never on this input
                const int base = rpB[t];
                unsigned* dp = &blist[(size_t)t * BCAP + gb];
                for (int i2 = 0; i2 < n; ++i2) dp[i2] = stage[base + i2];
            }
        }
        return;
    }

    // ---- gemm role (unchanged, proven) ----
    __bf16* w_lds = smem;

    for (int i = t; i < 4096; i += 512) {               // 8 iters
        float4 f = ((const float4*)W)[i];
        int n = i >> 5;
        int k = (i & 31) << 2;
        bf16x4 pk = { (__bf16)f.x, (__bf16)f.y, (__bf16)f.z, (__bf16)f.w };
        *(bf16x4*)&w_lds[n * 136 + k] = pk;
    }
    __syncthreads();

    const int wave = t >> 6;
    const int lane = t & 63;
    const int q = lane >> 4;
    const int mr = lane & 15;

    const int m0 = blockIdx.x * 128 + wave * 16;
    int arow = m0 + mr;
    if (arow >= N_NODES) arow = N_NODES - 1;

    f32x4 acc[8] = {};

#pragma unroll
    for (int ks = 0; ks < 4; ++ks) {
        const int k0 = ks * 32 + q * 8;
        const float4* ap = (const float4*)&A_f32[(size_t)arow * DIM + k0];
        float4 a0 = ap[0], a1 = ap[1];
        bf16x8 af;
        af[0] = (__bf16)a0.x; af[1] = (__bf16)a0.y;
        af[2] = (__bf16)a0.z; af[3] = (__bf16)a0.w;
        af[4] = (__bf16)a1.x; af[5] = (__bf16)a1.y;
        af[6] = (__bf16)a1.z; af[7] = (__bf16)a1.w;
#pragma unroll
        for (int nt = 0; nt < 8; ++nt) {
            bf16x8 bfr = *(const bf16x8*)&w_lds[(nt * 16 + mr) * 136 + k0];
            acc[nt] = __builtin_amdgcn_mfma_f32_16x16x32_bf16(af, bfr, acc[nt], 0, 0, 0);
        }
    }

    __syncthreads();
    float* lds_f = (float*)w_lds;
    const int nb = blockIdx.x * 128;

#pragma unroll
    for (int half = 0; half < 2; ++half) {
        if ((wave >> 2) == half) {
            int lw = wave & 3;
#pragma unroll
            for (int nt = 0; nt < 8; ++nt)
#pragma unroll
                for (int r = 0; r < 4; ++r)
                    lds_f[(lw * 16 + q * 4 + r) * 132 + nt * 16 + mr] = acc[nt][r];
        }
        __syncthreads();
        for (int i = t; i < 2048; i += 512) {
            int lr = i >> 5;
            int cg = (i & 31) << 2;
            int grow = nb + half * 64 + lr;
            if (grow < N_NODES) {
                float4 v = *(const float4*)&lds_f[lr * 132 + cg];
                float4 b4 = *(const float4*)&bias[cg];
                bf16x4 o;
                o[0] = (__bf16)fmaxf(v.x + b4.x, 0.f);
                o[1] = (__bf16)fmaxf(v.y + b4.y, 0.f);
                o[2] = (__bf16)fmaxf(v.z + b4.z, 0.f);
                o[3] = (__bf16)fmaxf(v.w + b4.w, 0.f);
                *(bf16x4*)&out_bf16[(size_t)grow * DIM + cg] = o;
            }
        }
        __syncthreads();
    }
}

// ===========================================================================
// K2+K3 FUSED, R7 front-end: block loads its pre-localized edge list
// (coalesced), builds an exact per-node CSR in LDS (128-bin hist + scan +
// scatter, runs 8-aligned, pads = zero-row sentinel), then the proven
// batch-8 gather + MFMA GEMM2 + bias + relu. All slot/counter global loads
// and ballot compaction from R3 are gone.
// ===========================================================================
__global__ __launch_bounds__(512, 4) void agg_gemm2_k(
    const __bf16* __restrict__ h,
    const unsigned* __restrict__ blist,
    const int* __restrict__ bcnt,
    const float* __restrict__ eps_p,
    const __bf16* __restrict__ Wb,
    const float* __restrict__ bias,
    float* __restrict__ out)
{
    __shared__ __align__(16) __bf16 lds[2 * 128 * 136];       // 69.6 KB [W | A]
    __shared__ __align__(16) unsigned short slist[3072];      // 6 KB sorted src
    __shared__ int histD[128];
    __shared__ int rp8[128];
    __shared__ int offD[128];
    __bf16* const w_lds = lds;
    __bf16* const a_lds = lds + 128 * 136;
    unsigned* const estage = (unsigned*)a_lds;                // aliased; dead before a_lds writes

    const int t = threadIdx.x;

    // ---- stage W tile first (drains under CSR build + aggregation) ----
    for (int i = t; i < 2048; i += 512) {
        int n = i >> 4;
        int kk = (i & 15) << 3;
        bf16x8 v = *(const bf16x8*)&Wb[n * DIM + kk];
        *(bf16x8*)&w_lds[n * 136 + kk] = v;
    }

    // ---- load this block's edge list (coalesced) ----
    int cnt = bcnt[blockIdx.x];
    if (cnt > BCAP) cnt = BCAP;
    for (int i = t; i < cnt; i += 512) estage[i] = blist[(size_t)blockIdx.x * BCAP + i];
    if (t < 128) histD[t] = 0;
    for (int i = t; i < 3072; i += 512) slist[i] = (unsigned short)N_NODES;  // sentinel
    __syncthreads();

    // ---- per-node histogram ----
    for (int i = t; i < cnt; i += 512) atomicAdd(&histD[(estage[i] >> 16) & 127], 1);
    __syncthreads();

    // ---- 8-aligned exclusive scan over 128 nodes ----
    const int hv = (t < 128) ? ((histD[t] + 7) & ~7) : 0;
    if (t < 128) rp8[t] = hv;
    __syncthreads();
    for (int d = 1; d < 128; d <<= 1) {
        int nv = 0;
        if (t < 128) nv = rp8[t] + ((t >= d) ? rp8[t - d] : 0);
        __syncthreads();
        if (t < 128) rp8[t] = nv;
        __syncthreads();
    }
    if (t < 128) { int b = rp8[t] - hv; rp8[t] = b; offD[t] = b; }
    __syncthreads();

    // ---- scatter src u16 into node-ordered runs ----
    for (int i = t; i < cnt; i += 512) {
        unsigned e = estage[i];
        int nl = (e >> 16) & 127;
        int p = atomicAdd(&offD[nl], 1);
        slist[p] = (unsigned short)(e & 0xFFFFu);
    }
    __syncthreads();           // estage dead from here; a_lds writable

    // ---- aggregate 16 nodes per wave -> bf16 rows in a_lds ----
    const int wave = t >> 6;
    const int lane = t & 63;
    const int ch = lane << 1;
    const int rowbase = blockIdx.x * 128 + wave * 16;
    const float eps = eps_p[0];

    for (int i = 0; i < 16; ++i) {
        const int nl = wave * 16 + i;
        const int node = rowbase + i;
        const int nd = (node < N_NODES) ? node : N_NODES;   // zero row if OOB
        const int deg = histD[nl];
        const int base = rp8[nl];
        const unsigned sv = *(const unsigned*)&h[(size_t)nd * DIM + ch];
        float ax = 0.f, ay = 0.f;
        for (int e = 0; e < deg; e += 8) {
            uint4 w = *(const uint4*)&slist[base + e];      // 16B-aligned broadcast
            int s0 = w.x & 0xFFFF, s1 = w.x >> 16;
            int s2 = w.y & 0xFFFF, s3 = w.y >> 16;
            int s4 = w.z & 0xFFFF, s5 = w.z >> 16;
            int s6 = w.w & 0xFFFF, s7 = w.w >> 16;
            unsigned v0 = *(const unsigned*)&h[(size_t)s0 * DIM + ch];
            unsigned v1 = *(const unsigned*)&h[(size_t)s1 * DIM + ch];
            unsigned v2 = *(const unsigned*)&h[(size_t)s2 * DIM + ch];
            unsigned v3 = *(const unsigned*)&h[(size_t)s3 * DIM + ch];
            unsigned v4 = *(const unsigned*)&h[(size_t)s4 * DIM + ch];
            unsigned v5 = *(const unsigned*)&h[(size_t)s5 * DIM + ch];
            unsigned v6 = *(const unsigned*)&h[(size_t)s6 * DIM + ch];
            unsigned v7 = *(const unsigned*)&h[(size_t)s7 * DIM + ch];
            ax += (bflo(v0) + bflo(v1)) + (bflo(v2) + bflo(v3))
                + (bflo(v4) + bflo(v5)) + (bflo(v6) + bflo(v7));
            ay += (bfhi(v0) + bfhi(v1)) + (bfhi(v2) + bfhi(v3))
                + (bfhi(v4) + bfhi(v5)) + (bfhi(v6) + bfhi(v7));
        }
        ax = 1.0f + eps * bflo(sv) + ax;
        ay = 1.0f + eps * bfhi(sv) + ay;
        bf16x2 o; o[0] = (__bf16)ax; o[1] = (__bf16)ay;
        *(bf16x2*)&a_lds[nl * 136 + ch] = o;                // own-wave row
    }

    __syncthreads();           // W staged; A rows own-wave

    const int q = lane >> 4;
    const int mr = lane & 15;

    f32x4 acc[8] = {};

#pragma unroll
    for (int ks = 0; ks < 4; ++ks) {
        const int k0 = ks * 32 + q * 8;
        bf16x8 af = *(const bf16x8*)&a_lds[(wave * 16 + mr) * 136 + k0];
#pragma unroll
        for (int nt = 0; nt < 8; ++nt) {
            bf16x8 bfr = *(const bf16x8*)&w_lds[(nt * 16 + mr) * 136 + k0];
            acc[nt] = __builtin_amdgcn_mfma_f32_16x16x32_bf16(af, bfr, acc[nt], 0, 0, 0);
        }
    }

    __syncthreads();
    float* lds_f = (float*)lds;
    const int nb = blockIdx.x * 128;

#pragma unroll
    for (int half = 0; half < 2; ++half) {
        if ((wave >> 2) == half) {
            int lw = wave & 3;
#pragma unroll
            for (int nt = 0; nt < 8; ++nt)
#pragma unroll
                for (int r = 0; r < 4; ++r)
                    lds_f[(lw * 16 + q * 4 + r) * 132 + nt * 16 + mr] = acc[nt][r];
        }
        __syncthreads();
        for (int i2 = t; i2 < 2048; i2 += 512) {
            int lr = i2 >> 5;
            int cg = (i2 & 31) << 2;
            int grow = nb + half * 64 + lr;
            if (grow < N_NODES) {
                float4 v = *(const float4*)&lds_f[lr * 132 + cg];
                float4 b4 = *(const float4*)&bias[cg];
                v.x = fmaxf(v.x + b4.x, 0.f);
                v.y = fmaxf(v.y + b4.y, 0.f);
                v.z = fmaxf(v.z + b4.z, 0.f);
                v.w = fmaxf(v.w + b4.w, 0.f);
                *(float4*)&out[(size_t)grow * DIM + cg] = v;
            }
        }
        __syncthreads();
    }
}

extern "C" void kernel_launch(void* const* d_in, const int* in_sizes, int n_in,
                              void* d_out, int out_size, void* d_ws, size_t ws_size,
                              hipStream_t stream) {
    const float* feats = (const float*)d_in[0];
    const int*   src   = (const int*)d_in[1];
    const int*   dst   = (const int*)d_in[2];
    const float* W_f   = (const float*)d_in[3];
    const float* b_f   = (const float*)d_in[4];
    const float* W_phy = (const float*)d_in[5];
    const float* b_phy = (const float*)d_in[6];
    const float* eps   = (const float*)d_in[7];
    float* out = (float*)d_out;

    const size_t HN = (size_t)(N_NODES + 1) * DIM;      // +1 zero row
    __bf16* h       = (__bf16*)d_ws;                                // 12.8 MB
    unsigned* blist = (unsigned*)(h + HN);                          // NB*BCAP*4 = 3.2 MB
    int* bcnt       = (int*)(blist + (size_t)NB * BCAP);            // 512 ints
    __bf16* Wb      = (__bf16*)(bcnt + 512);                        // 32 KB

    const int gblocks = (N_NODES + 127) / 128;          // 391
    const int fblocks = (N_EDGES / 8 + 511) / 512;      // 153

    hipMemsetAsync(bcnt, 0, 512 * sizeof(int), stream);

    gemm1_fill_k<<<gblocks + fblocks, 512, 0, stream>>>(
        feats, W_f, b_f, h, src, dst, blist, bcnt, W_phy, Wb, gblocks);

    agg_gemm2_k<<<gblocks, 512, 0, stream>>>(
        h, blist, bcnt, eps, Wb, b_phy, out);
}

// Round 8
// 132.175 us; speedup vs baseline: 1.2144x; 1.0128x over previous
//
#include <hip/hip_runtime.h>

#define N_NODES 50000
#define N_EDGES 625000
#define DIM 128
#define NB 391            // coarse buckets = agg blocks (node >> 7)
#define BCAP 2048         // edges per bucket list (expected 1598, +11 sigma)
#define SLCAP 4096        // padded u16 CSR capacity (max possible 3968)

typedef __bf16 bf16x8 __attribute__((ext_vector_type(8)));
typedef __bf16 bf16x4 __attribute__((ext_vector_type(4)));
typedef __bf16 bf16x2 __attribute__((ext_vector_type(2)));
typedef float f32x4 __attribute__((ext_vector_type(4)));

__device__ __forceinline__ float bflo(unsigned u) { return __uint_as_float(u << 16); }
__device__ __forceinline__ float bfhi(unsigned u) { return __uint_as_float(u & 0xffff0000u); }

// ===========================================================================
// K1: fused [GEMM1 | two-level edge bucketing] (R7 structure, proven:
// 152.3 -> 133.9 by eliminating per-edge global atomics).
// ===========================================================================
__global__ __launch_bounds__(512) void gemm1_fill_k(
    const float* __restrict__ A_f32,
    const float* __restrict__ W,
    const float* __restrict__ bias,
    __bf16* __restrict__ out_bf16,
    const int* __restrict__ src,
    const int* __restrict__ dst,
    unsigned* __restrict__ blist,     // [NB][BCAP] packed edges
    int* __restrict__ bcnt,           // [NB] list lengths
    const float* __restrict__ W_phy,
    __bf16* __restrict__ Wb,
    int gemm_blocks)
{
    __shared__ __align__(16) __bf16 smem[128 * 136];    // 34.8 KB, both roles
    const int t = threadIdx.x;

    if ((int)blockIdx.x >= gemm_blocks) {
        // ---- fill role: LDS two-level bucketing ----
        int* hist       = (int*)smem;                   // [512]
        int* scanA      = hist + 512;                   // [512]
        int* rpB        = scanA + 512;                  // [512]
        int* offB       = rpB + 512;                    // [512]
        unsigned* stage = (unsigned*)(offB + 512);      // [4096]

        if ((int)blockIdx.x == gemm_blocks) {
            if (t < 16) {                               // zero row N_NODES of h
                bf16x8 z = {};
                *(bf16x8*)&out_bf16[(size_t)N_NODES * DIM + t * 8] = z;
            }
            for (int i = t; i < 4096; i += 512) {       // W_phy fp32 -> bf16
                float4 f = ((const float4*)W_phy)[i];
                bf16x4 pk = { (__bf16)f.x, (__bf16)f.y, (__bf16)f.z, (__bf16)f.w };
                *(bf16x4*)&Wb[i * 4] = pk;
            }
        }

        hist[t] = 0;
        __syncthreads();

        const int idx = ((int)blockIdx.x - gemm_blocks) * 512 + t;
        const bool valid = idx < N_EDGES / 8;           // 625000 = 8*78125
        unsigned pk[8];
        int bk[8];
        if (valid) {
            int4 sa = ((const int4*)src)[idx * 2];
            int4 sb = ((const int4*)src)[idx * 2 + 1];
            int4 da = ((const int4*)dst)[idx * 2];
            int4 db = ((const int4*)dst)[idx * 2 + 1];
            pk[0] = ((unsigned)(da.x & 127) << 16) | (unsigned)sa.x; bk[0] = da.x >> 7;
            pk[1] = ((unsigned)(da.y & 127) << 16) | (unsigned)sa.y; bk[1] = da.y >> 7;
            pk[2] = ((unsigned)(da.z & 127) << 16) | (unsigned)sa.z; bk[2] = da.z >> 7;
            pk[3] = ((unsigned)(da.w & 127) << 16) | (unsigned)sa.w; bk[3] = da.w >> 7;
            pk[4] = ((unsigned)(db.x & 127) << 16) | (unsigned)sb.x; bk[4] = db.x >> 7;
            pk[5] = ((unsigned)(db.y & 127) << 16) | (unsigned)sb.y; bk[5] = db.y >> 7;
            pk[6] = ((unsigned)(db.z & 127) << 16) | (unsigned)sb.z; bk[6] = db.z >> 7;
            pk[7] = ((unsigned)(db.w & 127) << 16) | (unsigned)sb.w; bk[7] = db.w >> 7;
#pragma unroll
            for (int j = 0; j < 8; ++j) atomicAdd(&hist[bk[j]], 1);   // LDS
        }
        __syncthreads();

        // Hillis-Steele inclusive scan over 512 slots (buckets 391..511 zero)
        const int hv = hist[t];
        scanA[t] = hv;
        __syncthreads();
        for (int d = 1; d < 512; d <<= 1) {
            int nv = scanA[t] + ((t >= d) ? scanA[t - d] : 0);
            __syncthreads();
            scanA[t] = nv;
            __syncthreads();
        }
        rpB[t] = scanA[t] - hv;                         // exclusive base
        offB[t] = scanA[t] - hv;                        // running cursor
        __syncthreads();

        if (valid) {
#pragma unroll
            for (int j = 0; j < 8; ++j) {
                int p = atomicAdd(&offB[bk[j]], 1);     // LDS
                stage[p] = pk[j];
            }
        }
        __syncthreads();

        // copy-out: one global atomic per (block,bucket) run, burst writes
        if (t < NB) {
            int n = hist[t];
            if (n > 0) {
                int gb = atomicAdd(&bcnt[t], n);        // ~60k total device-wide
                int lim = BCAP - gb;
                if (n > lim) n = (lim > 0) ? lim : 0;   // paranoia; never on this input
                const int base = rpB[t];
                unsigned* dp = &blist[(size_t)t * BCAP + gb];
                for (int i2 = 0; i2 < n; ++i2) dp[i2] = stage[base + i2];
            }
        }
        return;
    }

    // ---- gemm role (unchanged, proven) ----
    __bf16* w_lds = smem;

    for (int i = t; i < 4096; i += 512) {               // 8 iters
        float4 f = ((const float4*)W)[i];
        int n = i >> 5;
        int k = (i & 31) << 2;
        bf16x4 pk = { (__bf16)f.x, (__bf16)f.y, (__bf16)f.z, (__bf16)f.w };
        *(bf16x4*)&w_lds[n * 136 + k] = pk;
    }
    __syncthreads();

    const int wave = t >> 6;
    const int lane = t & 63;
    const int q = lane >> 4;
    const int mr = lane & 15;

    const int m0 = blockIdx.x * 128 + wave * 16;
    int arow = m0 + mr;
    if (arow >= N_NODES) arow = N_NODES - 1;

    f32x4 acc[8] = {};

#pragma unroll
    for (int ks = 0; ks < 4; ++ks) {
        const int k0 = ks * 32 + q * 8;
        const float4* ap = (const float4*)&A_f32[(size_t)arow * DIM + k0];
        float4 a0 = ap[0], a1 = ap[1];
        bf16x8 af;
        af[0] = (__bf16)a0.x; af[1] = (__bf16)a0.y;
        af[2] = (__bf16)a0.z; af[3] = (__bf16)a0.w;
        af[4] = (__bf16)a1.x; af[5] = (__bf16)a1.y;
        af[6] = (__bf16)a1.z; af[7] = (__bf16)a1.w;
#pragma unroll
        for (int nt = 0; nt < 8; ++nt) {
            bf16x8 bfr = *(const bf16x8*)&w_lds[(nt * 16 + mr) * 136 + k0];
            acc[nt] = __builtin_amdgcn_mfma_f32_16x16x32_bf16(af, bfr, acc[nt], 0, 0, 0);
        }
    }

    __syncthreads();
    float* lds_f = (float*)w_lds;
    const int nb = blockIdx.x * 128;

#pragma unroll
    for (int half = 0; half < 2; ++half) {
        if ((wave >> 2) == half) {
            int lw = wave & 3;
#pragma unroll
            for (int nt = 0; nt < 8; ++nt)
#pragma unroll
                for (int r = 0; r < 4; ++r)
                    lds_f[(lw * 16 + q * 4 + r) * 132 + nt * 16 + mr] = acc[nt][r];
        }
        __syncthreads();
        for (int i = t; i < 2048; i += 512) {
            int lr = i >> 5;
            int cg = (i & 31) << 2;
            int grow = nb + half * 64 + lr;
            if (grow < N_NODES) {
                float4 v = *(const float4*)&lds_f[lr * 132 + cg];
                float4 b4 = *(const float4*)&bias[cg];
                bf16x4 o;
                o[0] = (__bf16)fmaxf(v.x + b4.x, 0.f);
                o[1] = (__bf16)fmaxf(v.y + b4.y, 0.f);
                o[2] = (__bf16)fmaxf(v.z + b4.z, 0.f);
                o[3] = (__bf16)fmaxf(v.w + b4.w, 0.f);
                *(bf16x4*)&out_bf16[(size_t)grow * DIM + cg] = o;
            }
        }
        __syncthreads();
    }
}

// ===========================================================================
// K2+K3 FUSED. R8 delta: CSR runs padded to 16 (was 8) and the gather batch
// widened to 16 rows in flight per wave -- regime test for latency- vs
// BW-bound gather. 87% of nodes (deg<=16) finish in ONE fully-parallel
// batch; pads hit the zero row (L1-resident after first touch, ~free).
// ===========================================================================
__global__ __launch_bounds__(512, 4) void agg_gemm2_k(
    const __bf16* __restrict__ h,
    const unsigned* __restrict__ blist,
    const int* __restrict__ bcnt,
    const float* __restrict__ eps_p,
    const __bf16* __restrict__ Wb,
    const float* __restrict__ bias,
    float* __restrict__ out)
{
    __shared__ __align__(16) __bf16 lds[2 * 128 * 136];       // 69.6 KB [W | A]
    __shared__ __align__(16) unsigned short slist[SLCAP];     // 8 KB sorted src
    __shared__ int histD[128];
    __shared__ int rp16[128];
    __shared__ int offD[128];
    __bf16* const w_lds = lds;
    __bf16* const a_lds = lds + 128 * 136;
    unsigned* const estage = (unsigned*)a_lds;                // aliased; dead before a_lds writes

    const int t = threadIdx.x;

    // ---- stage W tile first (drains under CSR build + aggregation) ----
    for (int i = t; i < 2048; i += 512) {
        int n = i >> 4;
        int kk = (i & 15) << 3;
        bf16x8 v = *(const bf16x8*)&Wb[n * DIM + kk];
        *(bf16x8*)&w_lds[n * 136 + kk] = v;
    }

    // ---- load this block's edge list (coalesced) ----
    int cnt = bcnt[blockIdx.x];
    if (cnt > BCAP) cnt = BCAP;
    for (int i = t; i < cnt; i += 512) estage[i] = blist[(size_t)blockIdx.x * BCAP + i];
    if (t < 128) histD[t] = 0;
    for (int i = t; i < SLCAP; i += 512) slist[i] = (unsigned short)N_NODES;  // sentinel
    __syncthreads();

    // ---- per-node histogram ----
    for (int i = t; i < cnt; i += 512) atomicAdd(&histD[(estage[i] >> 16) & 127], 1);
    __syncthreads();

    // ---- 16-aligned exclusive scan over 128 nodes ----
    const int hv = (t < 128) ? ((histD[t] + 15) & ~15) : 0;
    if (t < 128) rp16[t] = hv;
    __syncthreads();
    for (int d = 1; d < 128; d <<= 1) {
        int nv = 0;
        if (t < 128) nv = rp16[t] + ((t >= d) ? rp16[t - d] : 0);
        __syncthreads();
        if (t < 128) rp16[t] = nv;
        __syncthreads();
    }
    if (t < 128) { int b = rp16[t] - hv; rp16[t] = b; offD[t] = b; }
    __syncthreads();

    // ---- scatter src u16 into node-ordered, 16-aligned runs ----
    for (int i = t; i < cnt; i += 512) {
        unsigned e = estage[i];
        int nl = (e >> 16) & 127;
        int p = atomicAdd(&offD[nl], 1);
        slist[p] = (unsigned short)(e & 0xFFFFu);
    }
    __syncthreads();           // estage dead from here; a_lds writable

    // ---- aggregate 16 nodes per wave -> bf16 rows in a_lds ----
    const int wave = t >> 6;
    const int lane = t & 63;
    const int ch = lane << 1;
    const int rowbase = blockIdx.x * 128 + wave * 16;
    const float eps = eps_p[0];

    for (int i = 0; i < 16; ++i) {
        const int nl = wave * 16 + i;
        const int node = rowbase + i;
        const int nd = (node < N_NODES) ? node : N_NODES;   // zero row if OOB
        const int deg = histD[nl];
        const int base = rp16[nl];
        const unsigned sv = *(const unsigned*)&h[(size_t)nd * DIM + ch];
        float ax = 0.f, ay = 0.f;
        for (int e = 0; e < deg; e += 16) {                 // 16 rows in flight
            uint4 w0 = *(const uint4*)&slist[base + e];     // 16B-aligned broadcast
            uint4 w1 = *(const uint4*)&slist[base + e + 8];
            int s0 = w0.x & 0xFFFF, s1 = w0.x >> 16;
            int s2 = w0.y & 0xFFFF, s3 = w0.y >> 16;
            int s4 = w0.z & 0xFFFF, s5 = w0.z >> 16;
            int s6 = w0.w & 0xFFFF, s7 = w0.w >> 16;
            int s8 = w1.x & 0xFFFF, s9 = w1.x >> 16;
            int sA = w1.y & 0xFFFF, sB = w1.y >> 16;
            int sC = w1.z & 0xFFFF, sD = w1.z >> 16;
            int sE = w1.w & 0xFFFF, sF = w1.w >> 16;
            unsigned v0 = *(const unsigned*)&h[(size_t)s0 * DIM + ch];
            unsigned v1 = *(const unsigned*)&h[(size_t)s1 * DIM + ch];
            unsigned v2 = *(const unsigned*)&h[(size_t)s2 * DIM + ch];
            unsigned v3 = *(const unsigned*)&h[(size_t)s3 * DIM + ch];
            unsigned v4 = *(const unsigned*)&h[(size_t)s4 * DIM + ch];
            unsigned v5 = *(const unsigned*)&h[(size_t)s5 * DIM + ch];
            unsigned v6 = *(const unsigned*)&h[(size_t)s6 * DIM + ch];
            unsigned v7 = *(const unsigned*)&h[(size_t)s7 * DIM + ch];
            unsigned v8 = *(const unsigned*)&h[(size_t)s8 * DIM + ch];
            unsigned v9 = *(const unsigned*)&h[(size_t)s9 * DIM + ch];
            unsigned vA = *(const unsigned*)&h[(size_t)sA * DIM + ch];
            unsigned vB = *(const unsigned*)&h[(size_t)sB * DIM + ch];
            unsigned vC = *(const unsigned*)&h[(size_t)sC * DIM + ch];
            unsigned vD = *(const unsigned*)&h[(size_t)sD * DIM + ch];
            unsigned vE = *(const unsigned*)&h[(size_t)sE * DIM + ch];
            unsigned vF = *(const unsigned*)&h[(size_t)sF * DIM + ch];
            ax += ((bflo(v0) + bflo(v1)) + (bflo(v2) + bflo(v3)))
                + ((bflo(v4) + bflo(v5)) + (bflo(v6) + bflo(v7)))
                + ((bflo(v8) + bflo(v9)) + (bflo(vA) + bflo(vB)))
                + ((bflo(vC) + bflo(vD)) + (bflo(vE) + bflo(vF)));
            ay += ((bfhi(v0) + bfhi(v1)) + (bfhi(v2) + bfhi(v3)))
                + ((bfhi(v4) + bfhi(v5)) + (bfhi(v6) + bfhi(v7)))
                + ((bfhi(v8) + bfhi(v9)) + (bfhi(vA) + bfhi(vB)))
                + ((bfhi(vC) + bfhi(vD)) + (bfhi(vE) + bfhi(vF)));
        }
        ax = 1.0f + eps * bflo(sv) + ax;
        ay = 1.0f + eps * bfhi(sv) + ay;
        bf16x2 o; o[0] = (__bf16)ax; o[1] = (__bf16)ay;
        *(bf16x2*)&a_lds[nl * 136 + ch] = o;                // own-wave row
    }

    __syncthreads();           // W staged; A rows own-wave

    const int q = lane >> 4;
    const int mr = lane & 15;

    f32x4 acc[8] = {};

#pragma unroll
    for (int ks = 0; ks < 4; ++ks) {
        const int k0 = ks * 32 + q * 8;
        bf16x8 af = *(const bf16x8*)&a_lds[(wave * 16 + mr) * 136 + k0];
#pragma unroll
        for (int nt = 0; nt < 8; ++nt) {
            bf16x8 bfr = *(const bf16x8*)&w_lds[(nt * 16 + mr) * 136 + k0];
            acc[nt] = __builtin_amdgcn_mfma_f32_16x16x32_bf16(af, bfr, acc[nt], 0, 0, 0);
        }
    }

    __syncthreads();
    float* lds_f = (float*)lds;
    const int nb = blockIdx.x * 128;

#pragma unroll
    for (int half = 0; half < 2; ++half) {
        if ((wave >> 2) == half) {
            int lw = wave & 3;
#pragma unroll
            for (int nt = 0; nt < 8; ++nt)
#pragma unroll
                for (int r = 0; r < 4; ++r)
                    lds_f[(lw * 16 + q * 4 + r) * 132 + nt * 16 + mr] = acc[nt][r];
        }
        __syncthreads();
        for (int i2 = t; i2 < 2048; i2 += 512) {
            int lr = i2 >> 5;
            int cg = (i2 & 31) << 2;
            int grow = nb + half * 64 + lr;
            if (grow < N_NODES) {
                float4 v = *(const float4*)&lds_f[lr * 132 + cg];
                float4 b4 = *(const float4*)&bias[cg];
                v.x = fmaxf(v.x + b4.x, 0.f);
                v.y = fmaxf(v.y + b4.y, 0.f);
                v.z = fmaxf(v.z + b4.z, 0.f);
                v.w = fmaxf(v.w + b4.w, 0.f);
                *(float4*)&out[(size_t)grow * DIM + cg] = v;
            }
        }
        __syncthreads();
    }
}

extern "C" void kernel_launch(void* const* d_in, const int* in_sizes, int n_in,
                              void* d_out, int out_size, void* d_ws, size_t ws_size,
                              hipStream_t stream) {
    const float* feats = (const float*)d_in[0];
    const int*   src   = (const int*)d_in[1];
    const int*   dst   = (const int*)d_in[2];
    const float* W_f   = (const float*)d_in[3];
    const float* b_f   = (const float*)d_in[4];
    const float* W_phy = (const float*)d_in[5];
    const float* b_phy = (const float*)d_in[6];
    const float* eps   = (const float*)d_in[7];
    float* out = (float*)d_out;

    const size_t HN = (size_t)(N_NODES + 1) * DIM;      // +1 zero row
    __bf16* h       = (__bf16*)d_ws;                                // 12.8 MB
    unsigned* blist = (unsigned*)(h + HN);                          // NB*BCAP*4 = 3.2 MB
    int* bcnt       = (int*)(blist + (size_t)NB * BCAP);            // 512 ints
    __bf16* Wb      = (__bf16*)(bcnt + 512);                        // 32 KB

    const int gblocks = (N_NODES + 127) / 128;          // 391
    const int fblocks = (N_EDGES / 8 + 511) / 512;      // 153

    hipMemsetAsync(bcnt, 0, 512 * sizeof(int), stream);

    gemm1_fill_k<<<gblocks + fblocks, 512, 0, stream>>>(
        feats, W_f, b_f, h, src, dst, blist, bcnt, W_phy, Wb, gblocks);

    agg_gemm2_k<<<gblocks, 512, 0, stream>>>(
        h, blist, bcnt, eps, Wb, b_phy, out);
}